// Round 1
// baseline (661.120 us; speedup 1.0000x reference)
//
#include <hip/hip_runtime.h>

#define N_NODES 50000
#define N_EDGES 800000

static inline size_t align256(size_t x) { return (x + 255) & ~(size_t)255; }

// ---------------- CSR build ----------------

__global__ void count_kernel(const int* __restrict__ dst, int* __restrict__ counts, int E) {
    int e = blockIdx.x * blockDim.x + threadIdx.x;
    if (e < E) atomicAdd(&counts[dst[e]], 1);
}

__global__ void scan_kernel(const int* __restrict__ counts, int* __restrict__ row_ptr, int n) {
    __shared__ int sd[1024];
    __shared__ int carry_s;
    if (threadIdx.x == 0) { carry_s = 0; row_ptr[0] = 0; }
    __syncthreads();
    for (int base = 0; base < n; base += 1024) {
        int i = base + (int)threadIdx.x;
        int v = (i < n) ? counts[i] : 0;
        sd[threadIdx.x] = v;
        __syncthreads();
        #pragma unroll
        for (int off = 1; off < 1024; off <<= 1) {
            int t = 0;
            if ((int)threadIdx.x >= off) t = sd[threadIdx.x - off];
            __syncthreads();
            sd[threadIdx.x] += t;
            __syncthreads();
        }
        if (i < n) row_ptr[i + 1] = carry_s + sd[threadIdx.x];
        __syncthreads();
        if (threadIdx.x == 1023) carry_s += sd[1023];
        __syncthreads();
    }
}

__global__ void prep_kernel(const int* __restrict__ row_ptr, const int* __restrict__ counts,
                            int* __restrict__ cursor, float* __restrict__ dis, int N) {
    int v = blockIdx.x * blockDim.x + threadIdx.x;
    if (v < N) {
        cursor[v] = row_ptr[v];
        dis[v] = rsqrtf((float)(counts[v] + 1));   // deg includes self-loop, >= 1
    }
}

__global__ void fill_kernel(const int* __restrict__ src, const int* __restrict__ dst,
                            int* __restrict__ cursor, int* __restrict__ col, int E) {
    int e = blockIdx.x * blockDim.x + threadIdx.x;
    if (e < E) {
        int p = atomicAdd(&cursor[dst[e]], 1);
        col[p] = src[e];
    }
}

// ---------------- GEMM with fused dis-row-scale: G = diag(dis) * (A @ W) ----------------
// A: [M,K] row-major, W: [K,N] row-major, G: [M,N]. N % 64 == 0, K % 16 == 0.

#define BM 64
#define BN 64
#define BK 16

__global__ __launch_bounds__(256) void gemm_scale(
    const float* __restrict__ A, const float* __restrict__ W,
    const float* __restrict__ dis, float* __restrict__ G,
    int M, int N, int K) {
    __shared__ float As[BK][BM + 1];
    __shared__ float Bs[BK][BN];

    int t  = threadIdx.x;
    int tx = t & 15, ty = t >> 4;
    int m0 = blockIdx.y * BM;
    int n0 = blockIdx.x * BN;

    int arow = t >> 2;          // 0..63 : row within A tile
    int akq  = (t & 3) * 4;     // 0,4,8,12 : k quad
    int brow = t >> 4;          // 0..15 : k within B tile
    int bcol = (t & 15) * 4;    // 0..60 : col quad

    float acc[4][4] = {};

    for (int kt = 0; kt < K; kt += BK) {
        float4 av = make_float4(0.f, 0.f, 0.f, 0.f);
        if (m0 + arow < M)
            av = *(const float4*)(A + (long)(m0 + arow) * K + kt + akq);
        As[akq + 0][arow] = av.x;
        As[akq + 1][arow] = av.y;
        As[akq + 2][arow] = av.z;
        As[akq + 3][arow] = av.w;

        float4 bv = *(const float4*)(W + (long)(kt + brow) * N + n0 + bcol);
        *(float4*)&Bs[brow][bcol] = bv;

        __syncthreads();
        #pragma unroll
        for (int k = 0; k < BK; ++k) {
            float a[4], b[4];
            #pragma unroll
            for (int i = 0; i < 4; ++i) a[i] = As[k][ty * 4 + i];
            #pragma unroll
            for (int j = 0; j < 4; ++j) b[j] = Bs[k][tx * 4 + j];
            #pragma unroll
            for (int i = 0; i < 4; ++i)
                #pragma unroll
                for (int j = 0; j < 4; ++j)
                    acc[i][j] += a[i] * b[j];
        }
        __syncthreads();
    }

    #pragma unroll
    for (int i = 0; i < 4; ++i) {
        int m = m0 + ty * 4 + i;
        if (m < M) {
            float s = dis[m];
            float4 o = make_float4(acc[i][0] * s, acc[i][1] * s, acc[i][2] * s, acc[i][3] * s);
            *(float4*)(G + (long)m * N + n0 + tx * 4) = o;
        }
    }
}

// ---------------- Aggregation: out[v] = act(dis[v]*(sum_{u->v} g[u] + g[v]) + b) ----------------
// One block per node, blockDim.x == D (64/128/256).

template <bool RELU>
__global__ void agg_kernel(const float* __restrict__ g, const int* __restrict__ row_ptr,
                           const int* __restrict__ col, const float* __restrict__ dis,
                           const float* __restrict__ bias, float* __restrict__ out,
                           int D) {
    int v = blockIdx.x;
    int j = threadIdx.x;
    int s = row_ptr[v], e = row_ptr[v + 1];

    float sum = g[(long)v * D + j];     // self-loop term
    int i = s;
    for (; i + 4 <= e; i += 4) {
        int u0 = col[i], u1 = col[i + 1], u2 = col[i + 2], u3 = col[i + 3];
        float f0 = g[(long)u0 * D + j];
        float f1 = g[(long)u1 * D + j];
        float f2 = g[(long)u2 * D + j];
        float f3 = g[(long)u3 * D + j];
        sum += (f0 + f1) + (f2 + f3);
    }
    for (; i < e; ++i)
        sum += g[(long)col[i] * D + j];

    float r = dis[v] * sum + bias[j];
    if (RELU) r = fmaxf(r, 0.f);
    out[(long)v * D + j] = r;
}

// ---------------- launch ----------------

extern "C" void kernel_launch(void* const* d_in, const int* in_sizes, int n_in,
                              void* d_out, int out_size, void* d_ws, size_t ws_size,
                              hipStream_t stream) {
    const int N = N_NODES, E = N_EDGES;

    const float* x   = (const float*)d_in[0];
    const int*   ei  = (const int*)d_in[1];
    const int*   src = ei;
    const int*   dst = ei + E;
    const float* W1 = (const float*)d_in[2];  const float* b1 = (const float*)d_in[3];
    const float* W2 = (const float*)d_in[4];  const float* b2 = (const float*)d_in[5];
    const float* W3 = (const float*)d_in[6];  const float* b3 = (const float*)d_in[7];
    const float* W4 = (const float*)d_in[8];  const float* b4 = (const float*)d_in[9];
    float* out = (float*)d_out;

    // workspace carve-up
    char* w = (char*)d_ws;
    int*   counts  = (int*)w;    w += align256((size_t)N * 4);
    int*   row_ptr = (int*)w;    w += align256((size_t)(N + 1) * 4);
    int*   cursor  = (int*)w;    w += align256((size_t)N * 4);
    float* dis     = (float*)w;  w += align256((size_t)N * 4);
    int*   col     = (int*)w;    w += align256((size_t)E * 4);
    float* B1      = (float*)w;  w += align256((size_t)N * 256 * 4);  // g buffer
    float* B2      = (float*)w;  w += align256((size_t)N * 256 * 4);  // feat buffer (<=256)
    float* B3      = (float*)w;  w += align256((size_t)N * 64 * 4);   // feat buffer (64)

    // ---- CSR build (once per call; reused by all 4 layers) ----
    hipMemsetAsync(counts, 0, (size_t)N * 4, stream);
    count_kernel<<<(E + 255) / 256, 256, 0, stream>>>(dst, counts, E);
    scan_kernel<<<1, 1024, 0, stream>>>(counts, row_ptr, N);
    prep_kernel<<<(N + 255) / 256, 256, 0, stream>>>(row_ptr, counts, cursor, dis, N);
    fill_kernel<<<(E + 255) / 256, 256, 0, stream>>>(src, dst, cursor, col, E);

    const int gy = (N + BM - 1) / BM;   // 782

    // ---- layer 1: x[,128] @ W1[128,256] -> B2[,256], relu ----
    gemm_scale<<<dim3(256 / BN, gy), 256, 0, stream>>>(x, W1, dis, B1, N, 256, 128);
    agg_kernel<true><<<N, 256, 0, stream>>>(B1, row_ptr, col, dis, b1, B2, 256);

    // ---- layer 2: B2[,256] @ W2[256,64] -> B3[,64], relu ----
    gemm_scale<<<dim3(64 / BN, gy), 256, 0, stream>>>(B2, W2, dis, B1, N, 64, 256);
    agg_kernel<true><<<N, 64, 0, stream>>>(B1, row_ptr, col, dis, b2, B3, 64);

    // ---- layer 3: B3[,64] @ W3[64,256] -> B2[,256], relu ----
    gemm_scale<<<dim3(256 / BN, gy), 256, 0, stream>>>(B3, W3, dis, B1, N, 256, 64);
    agg_kernel<true><<<N, 256, 0, stream>>>(B1, row_ptr, col, dis, b3, B2, 256);

    // ---- layer 4: B2[,256] @ W4[256,128] -> d_out[,128], no relu ----
    gemm_scale<<<dim3(128 / BN, gy), 256, 0, stream>>>(B2, W4, dis, B1, N, 128, 256);
    agg_kernel<false><<<N, 128, 0, stream>>>(B1, row_ptr, col, dis, b4, out, 128);
}